// Round 1
// 1063.870 us; speedup vs baseline: 1.2536x; 1.2536x over previous
//
#include <hip/hip_runtime.h>
#include <hip/hip_bf16.h>

#define NPTS 8192
#define DIM 32
#define KKDE 32
#define KRIPS 16
#define DESTNUM 10

__device__ __forceinline__ unsigned long long shfl_xor_u64(unsigned long long v, int m) {
  int lo = __shfl_xor((int)(unsigned)(v & 0xFFFFFFFFull), m, 64);
  int hi = __shfl_xor((int)(unsigned)(v >> 32), m, 64);
  return (((unsigned long long)(unsigned)hi) << 32) | (unsigned)lo;
}

// DPP row (16-lane) rotate-based reductions: VALU-speed, rows align with subgroups.
template <int CTRL>
__device__ __forceinline__ int dpp_mov(int v) {
  return __builtin_amdgcn_update_dpp(0, v, CTRL, 0xF, 0xF, false);
}
__device__ __forceinline__ int row_max16(int v) {
  int t;
  t = dpp_mov<0x128>(v); v = (t > v) ? t : v;  // row_ror:8
  t = dpp_mov<0x124>(v); v = (t > v) ? t : v;  // row_ror:4
  t = dpp_mov<0x122>(v); v = (t > v) ? t : v;  // row_ror:2
  t = dpp_mov<0x121>(v); v = (t > v) ? t : v;  // row_ror:1
  return v;
}
__device__ __forceinline__ int row_min16(int v) {
  int t;
  t = dpp_mov<0x128>(v); v = (t < v) ? t : v;
  t = dpp_mov<0x124>(v); v = (t < v) ? t : v;
  t = dpp_mov<0x122>(v); v = (t < v) ? t : v;
  t = dpp_mov<0x121>(v); v = (t < v) ? t : v;
  return v;
}

// ---------------- dtype detector: is x bf16-packed or f32? ----------------
__global__ __launch_bounds__(64) void detect_kernel(const unsigned short* __restrict__ x,
                                                    int* __restrict__ flag) {
  int lane = threadIdx.x;
  unsigned u = x[2 * lane];
  int e = (u >> 7) & 0xFF;
  bool pass = (e >= 110 && e <= 130);
  unsigned long long b = __ballot(pass);
  if (lane == 0) flag[0] = (__popcll(b) >= 32) ? 1 : 0;
}

// ---------------- transpose: xT[q][p] = x[p][q] as f32 (exact) ----------------
__global__ __launch_bounds__(256) void tr_kernel(const unsigned short* __restrict__ xh,
                                                 const int* __restrict__ flag,
                                                 float* __restrict__ xT) {
  int e = blockIdx.x * 256 + threadIdx.x;  // < NPTS*DIM
  if (e >= NPTS * DIM) return;
  int p = e >> 5, q = e & 31;
  float v;
  if (flag[0] != 0) v = __uint_as_float(((unsigned)xh[e]) << 16);
  else v = ((const float*)xh)[e];
  xT[q * NPTS + p] = v;
}

// ---------------- kNN v5 (R16/R17 proven fastest): 4-wide vectorized + bracket select ----------------
__global__ __launch_bounds__(256) void knn_kernel(const float* __restrict__ xT,
                                                  float* __restrict__ kde,
                                                  int* __restrict__ rips) {
  __shared__ float row[NPTS];                  // 32 KB
  __shared__ int cnt[4];
  __shared__ unsigned long long cand[4 * 64];  // 2 KB
  __shared__ unsigned long long srt[4 * 32];   // 1 KB
  __shared__ unsigned long long fin[64];       // 512 B
  __shared__ float knnv[KKDE];
  __shared__ int knni[KKDE];
  __shared__ float xis[DIM];
  const int i = blockIdx.x;
  const int t = threadIdx.x;
  const int w = t >> 6, lane = t & 63;
  if (t < DIM) xis[t] = xT[t * NPTS + i];
  __syncthreads();
  float xi[DIM];
#pragma unroll
  for (int q = 0; q < DIM; ++q) xi[q] = xis[q];
  float sqi = 0.f;
#pragma unroll
  for (int q = 0; q < DIM; ++q) sqi = fmaf(xi[q], xi[q], sqi);
  const float4* xT4 = (const float4*)xT;
  float4* row4 = (float4*)row;
  for (int j4 = t; j4 < NPTS / 4; j4 += 256) {
    float d0 = 0.f, d1 = 0.f, d2 = 0.f, d3 = 0.f;
    float s0 = 0.f, s1 = 0.f, s2 = 0.f, s3 = 0.f;
#pragma unroll
    for (int q = 0; q < DIM; ++q) {
      float4 v = xT4[q * (NPTS / 4) + j4];
      const float xq = xi[q];
      d0 = fmaf(xq, v.x, d0); s0 = fmaf(v.x, v.x, s0);
      d1 = fmaf(xq, v.y, d1); s1 = fmaf(v.y, v.y, s1);
      d2 = fmaf(xq, v.z, d2); s2 = fmaf(v.z, v.z, s2);
      d3 = fmaf(xq, v.w, d3); s3 = fmaf(v.w, v.w, s3);
    }
    // j==i component: v==xi[q] bitwise -> dot==sqi==sqj -> fmaf(-2,s,2s)==0 exactly
    float4 o;
    o.x = fmaxf(fmaf(-2.f, d0, sqi + s0), 0.f);
    o.y = fmaxf(fmaf(-2.f, d1, sqi + s1), 0.f);
    o.z = fmaxf(fmaf(-2.f, d2, sqi + s2), 0.f);
    o.w = fmaxf(fmaf(-2.f, d3, sqi + s3), 0.f);
    row4[j4] = o;
  }
  __syncthreads();
  const float4* rowf4 = (const float4*)row;
  unsigned lo = 0u, hi = 0x7F800000u;
  int chi = 2048;
  while (chi > 64 && (hi - lo) > 1u) {
    const unsigned mid = lo + ((hi - lo) >> 1);
    int c = 0;
#pragma unroll
    for (int s = 0; s < 8; ++s) {
      float4 v = rowf4[(w << 9) + (s << 6) + lane];
      c += (__float_as_uint(v.x) <= mid) ? 1 : 0;
      c += (__float_as_uint(v.y) <= mid) ? 1 : 0;
      c += (__float_as_uint(v.z) <= mid) ? 1 : 0;
      c += (__float_as_uint(v.w) <= mid) ? 1 : 0;
    }
#pragma unroll
    for (int m = 1; m <= 32; m <<= 1) c += __shfl_xor(c, m, 64);
    if (c >= 32) { hi = mid; chi = c; } else { lo = mid; }
  }
  if (lane == 0) cnt[w] = 0;
  cand[(w << 6) | lane] = ~0ull;
#pragma unroll
  for (int s = 0; s < 8; ++s) {
    const int fidx = (w << 9) + (s << 6) + lane;
    float4 v = rowf4[fidx];
    const unsigned b0 = __float_as_uint(v.x), b1 = __float_as_uint(v.y);
    const unsigned b2 = __float_as_uint(v.z), b3 = __float_as_uint(v.w);
    if (b0 <= hi) {
      int pos = atomicAdd(&cnt[w], 1);
      if (pos < 64) cand[(w << 6) + pos] = (((unsigned long long)b0) << 32) | (unsigned)(fidx * 4 + 0);
    }
    if (b1 <= hi) {
      int pos = atomicAdd(&cnt[w], 1);
      if (pos < 64) cand[(w << 6) + pos] = (((unsigned long long)b1) << 32) | (unsigned)(fidx * 4 + 1);
    }
    if (b2 <= hi) {
      int pos = atomicAdd(&cnt[w], 1);
      if (pos < 64) cand[(w << 6) + pos] = (((unsigned long long)b2) << 32) | (unsigned)(fidx * 4 + 2);
    }
    if (b3 <= hi) {
      int pos = atomicAdd(&cnt[w], 1);
      if (pos < 64) cand[(w << 6) + pos] = (((unsigned long long)b3) << 32) | (unsigned)(fidx * 4 + 3);
    }
  }
  unsigned long long v = cand[(w << 6) | lane];
#pragma unroll
  for (int k = 2; k <= 64; k <<= 1) {
#pragma unroll
    for (int j = 32; j > 0; j >>= 1) {
      if (j >= k) continue;
      unsigned long long o = shfl_xor_u64(v, j);
      bool keepMin = (((lane & k) == 0) == ((lane & j) == 0));
      v = keepMin ? (v < o ? v : o) : (v > o ? v : o);
    }
  }
  if (lane < 32) srt[(w << 5) | lane] = v;
  __syncthreads();
  if (w < 2) {
    const unsigned long long* A = &srt[(w * 2) << 5];
    const unsigned long long* B = &srt[(w * 2 + 1) << 5];
    unsigned long long m = (lane < 32) ? A[lane] : B[63 - lane];
#pragma unroll
    for (int j = 32; j > 0; j >>= 1) {
      unsigned long long o = shfl_xor_u64(m, j);
      bool keepMin = ((lane & j) == 0);
      m = keepMin ? (m < o ? m : o) : (m > o ? m : o);
    }
    if (lane < 32) fin[(w << 5) | lane] = m;
  }
  __syncthreads();
  if (w == 0) {
    unsigned long long m = (lane < 32) ? fin[lane] : fin[32 + (63 - lane)];
#pragma unroll
    for (int j = 32; j > 0; j >>= 1) {
      unsigned long long o = shfl_xor_u64(m, j);
      bool keepMin = ((lane & j) == 0);
      m = keepMin ? (m < o ? m : o) : (m > o ? m : o);
    }
    if (lane < 32) {
      knnv[lane] = __uint_as_float((unsigned)(m >> 32));
      knni[lane] = (int)(m & 0x1FFFull);
    }
  }
  __syncthreads();
  if (t == 0) {
    float s = 0.f;
    for (int k = 0; k < KKDE; ++k) s += expf(knnv[k] * -0.015625f);  // exp(-d2/64), ascending
    kde[i] = s;
  }
  if (t < KRIPS) rips[i * KRIPS + t] = knni[t];
}

// ---------------- prep: fused max + normalize + death-init + argmin (R18 proven) ----------------
__global__ __launch_bounds__(256) void prep_kernel(float* __restrict__ kde,
                                                   int* __restrict__ death,
                                                   int* __restrict__ scali) {
  __shared__ float red[256];
  __shared__ unsigned long long red64[256];
  __shared__ float kmaxS;
  const int t = threadIdx.x;
  float m = 0.f;
  for (int p = t; p < NPTS; p += 256) m = fmaxf(m, kde[p]);
  red[t] = m;
  __syncthreads();
  for (int s = 128; s; s >>= 1) {
    if (t < s) red[t] = fmaxf(red[t], red[t + s]);
    __syncthreads();
  }
  if (t == 0) kmaxS = red[0];
  __syncthreads();
  const float km = kmaxS;
  unsigned long long best = ~0ull;
  for (int p = t; p < NPTS; p += 256) {
    float v = kde[p] / km;
    kde[p] = v;
    death[p] = -1;
    unsigned long long kk = (((unsigned long long)__float_as_uint(v)) << 32) | (unsigned)p;
    if (kk < best) best = kk;
  }
  red64[t] = best;
  __syncthreads();
  for (int s = 128; s; s >>= 1) {
    if (t < s && red64[t + s] < red64[t]) red64[t] = red64[t + s];
    __syncthreads();
  }
  if (t == 0) scali[0] = (int)(red64[0] & 0xFFFFFFFFull);
}

// ---------------- bitonic sort: order = argsort(-kde) (stable), rank = inverse ----------------
__global__ __launch_bounds__(256) void sort_kernel(const float* __restrict__ kde,
                                                   int* __restrict__ order,
                                                   int* __restrict__ rankp) {
  __shared__ float kv[NPTS];            // 32 KB
  __shared__ unsigned short ki[NPTS];   // 16 KB
  int t = threadIdx.x;
  for (int p = t; p < NPTS; p += 256) { kv[p] = kde[p]; ki[p] = (unsigned short)p; }
  __syncthreads();
  for (int size = 2; size <= NPTS; size <<= 1) {
    for (int stride = size >> 1; stride > 0; stride >>= 1) {
      for (int q = t; q < NPTS / 2; q += 256) {
        int lo = ((q & ~(stride - 1)) << 1) | (q & (stride - 1));
        int hi = lo + stride;
        float va = kv[lo], vb = kv[hi];
        int ia = ki[lo], ib = ki[hi];
        bool aFirst = (va > vb) || (va == vb && ia < ib);
        bool up = ((lo & size) == 0);
        if (up != aFirst) {
          kv[lo] = vb; kv[hi] = va;
          ki[lo] = (unsigned short)ib; ki[hi] = (unsigned short)ia;
        }
      }
      __syncthreads();
    }
  }
  for (int p = t; p < NPTS; p += 256) {
    int idx = ki[p];
    order[p] = idx;
    rankp[idx] = p;
  }
}

// ---------------- ordered neighbor stream (flat: [t*16 + kk]) ----------------
// NOW stores the neighbor's RANK (13 bits) | valid<<15 | hazard<<14, where
// hazard = valid && neighbor rank falls in the same 16-aligned window as t
// (= the scan's batch prefetch window -> prefetched root read may be stale).
__global__ __launch_bounds__(256) void onbr_kernel(const int* __restrict__ order,
                                                   const int* __restrict__ rankp,
                                                   const int* __restrict__ rips,
                                                   unsigned short* __restrict__ onbr) {
  int e = blockIdx.x * 256 + threadIdx.x;  // e < NPTS*KRIPS
  if (e >= NPTS * KRIPS) return;
  int t = e >> 4, kk = e & 15;
  int i = order[t];
  int nbr = rips[i * KRIPS + kk];
  int r = rankp[nbr];
  unsigned short v = (unsigned short)r;
  if (r < t) {  // self has rank == t -> invalid, matching ref
    v |= 0x8000;
    if ((r >> 4) == (t >> 4)) v |= 0x4000;  // hazard: same prefetch window
  }
  onbr[e] = v;
}

// ---------------- persistence scan v2: rank-indexed union-find ----------------
// Key properties exploited:
//  * order is kde-descending => densest root == minimum rank (integer compare,
//    no kde gathers). Distinct roots have distinct ranks, no tie ambiguity.
//  * every member of a cluster rooted at rank r has rank in (r, now): winner of
//    any merge is the min-rank root, so members only ever point "backwards".
//    => depth<=1 repair after a merge scans only the span (rcX, pos), not all 8192.
//  * batch-level prefetch of the 4 calls' root reads (1x ~120cy LDS latency per
//    16 positions instead of 4x); staleness within the window is exactly the
//    precomputed hazard bit; any slow event clears `cln` -> re-read.
//  * DPP row_ror reductions (VALU) replace ds_swizzle shuffle chains.
__global__ __launch_bounds__(64) void scan_kernel(const int* __restrict__ order,
                                                  const unsigned short* __restrict__ onbr,
                                                  int* __restrict__ death,
                                                  const int* __restrict__ scali) {
  __shared__ unsigned short rootR[NPTS];   // 16 KB, indexed by rank -> root rank
  __shared__ unsigned short orderS[NPTS];  // 16 KB, rank -> point id
  const int lane = threadIdx.x;
  for (int p = lane; p < NPTS; p += 64) {
    rootR[p] = (unsigned short)p;
    orderS[p] = (unsigned short)order[p];
  }
  __syncthreads();
  const int sub = lane >> 4;  // subgroup = DPP row = one position per call

  auto process = [&](unsigned short D, int pref, int posBase, bool& cln) {
    const int nbr = D & 0x1FFF;
    const bool valid = (D & 0x8000) != 0;
    const bool hz = (D & 0x4000) != 0;
    int rd = cln ? pref : (int)rootR[nbr];
    const int rv = row_max16(valid ? rd : -1);
    const bool uniOk = !valid || (rd == rv);
    const unsigned long long uniB = __ballot(uniOk);
    const unsigned long long hzB = __ballot(hz);
    const unsigned long long badB = (~uniB) | hzB;
    if (badB == 0ull) {  // all 4 rows uniform, no hazards: pure attach
      if ((lane & 15) == 0 && rv >= 0) rootR[posBase + sub] = (unsigned short)rv;
      return;
    }
    const int sstar = (__ffsll(badB) - 1) >> 4;  // first dirty row
    // rows < sstar are hazard-free & uniform: commit their attaches now
    if ((lane & 15) == 0 && sub < sstar && rv >= 0)
      rootR[posBase + sub] = (unsigned short)rv;
    cln = false;
    // hazard lanes may hold stale values (prefetch OR pre-call read predates
    // same-window writes). Re-read them AFTER the commits above.
    if (hzB != 0ull) {
      const int f = (int)rootR[nbr];
      rd = hz ? f : rd;
    }
    const unsigned long long vbAll = __ballot(valid);
    for (int s = sstar; s < 4; ++s) {
      const int pos = posBase + s;
      const unsigned long long smask = 0xFFFFull << (s << 4);
      const unsigned long long vb = vbAll & smask;
      if (vb == 0ull) continue;  // birth: rootR[pos] stays pos
      const int cl = __ffsll(vb) - 1;
      const int gc = __builtin_amdgcn_readlane(rd, cl);
      const unsigned long long uni2 = __ballot(!valid || rd == gc);
      if ((uni2 & smask) == smask) {  // all valid roots equal: attach
        if (lane == (s << 4)) rootR[pos] = (unsigned short)gc;
        if (nbr == pos) rd = gc;  // patch later rows' stale view of pos
      } else {                        // merge: winner = min rank (densest)
        const int g = __builtin_amdgcn_readlane(row_min16(valid ? rd : 0x7FFFFFFF), s << 4);
        const bool dy = (sub == s) && valid && (rd != g);
        if (dy) {
          const int pid = orderS[rd];           // dying root's point id
          rootR[rd] = (unsigned short)g;
          death[pid] = (int)orderS[pos];        // dies at current point
        }
        if (lane == (s << 4)) rootR[pos] = (unsigned short)g;
        unsigned long long db = __ballot(dy);
        if (nbr == pos) rd = g;  // patch attach-of-pos for later rows
        while (db != 0ull) {     // one pass per DISTINCT dying root
          const int dl = __ffsll(db) - 1;
          const int rcX = __builtin_amdgcn_readlane(rd, dl);
          db &= ~__ballot(rd == rcX);
          // members of rcX all lie in (rcX, pos): span-limited relabel
          for (int r = rcX + 1 + lane; r < pos; r += 64)
            if (rootR[r] == (unsigned short)rcX) rootR[r] = (unsigned short)g;
          if (rd == rcX) rd = g;  // patch later rows pointing at rcX/members
        }
      }
    }
  };

  unsigned short D0 = onbr[lane], D1 = onbr[64 + lane],
                 D2 = onbr[128 + lane], D3 = onbr[192 + lane];
  for (int b = 0; b < NPTS / 16; ++b) {
    unsigned short N0 = 0, N1 = 0, N2 = 0, N3 = 0;
    if (b + 1 < NPTS / 16) {
      const int nb = (b + 1) * 256 + lane;
      N0 = onbr[nb]; N1 = onbr[nb + 64]; N2 = onbr[nb + 128]; N3 = onbr[nb + 192];
    }
    // batch-top prefetch of all 4 calls' root reads (one LDS latency)
    const int p0 = (int)rootR[D0 & 0x1FFF];
    const int p1 = (int)rootR[D1 & 0x1FFF];
    const int p2 = (int)rootR[D2 & 0x1FFF];
    const int p3 = (int)rootR[D3 & 0x1FFF];
    bool cln = true;
    const int base = b << 4;
    process(D0, p0, base, cln);
    process(D1, p1, base + 4, cln);
    process(D2, p2, base + 8, cln);
    process(D3, p3, base + 12, cln);
    D0 = N0; D1 = N1; D2 = N2; D3 = N3;
  }
  if (lane == 0) death[orderS[0]] = scali[0];  // essential pair
}

// ---------------- loss: top-10 persistence via LDS-staged pers (R17 proven) ----------------
__global__ __launch_bounds__(256) void loss_kernel(const float* __restrict__ kde,
                                                   const int* __restrict__ death,
                                                   float* __restrict__ out) {
  __shared__ float persS[NPTS];  // 32 KB
  __shared__ float redv[256];
  __shared__ int redi[256];
  const int t = threadIdx.x;
  for (int p = t; p < NPTS; p += 256) {
    int d = death[p];
    persS[p] = (d < 0) ? -__builtin_inff() : kde[p] - kde[d];
  }
  __syncthreads();
  int chosen[DESTNUM];
  for (int k = 0; k < DESTNUM; ++k) {
    float bv = -__builtin_inff();
    int bi = 1 << 30;
    for (int p = t; p < NPTS; p += 256) {
      float pv = persS[p];
      if (pv > bv || (pv == bv && p < bi)) { bv = pv; bi = p; }
    }
    redv[t] = bv; redi[t] = bi;
    __syncthreads();
    for (int s = 128; s; s >>= 1) {
      if (t < s) {
        if (redv[t + s] > redv[t] || (redv[t + s] == redv[t] && redi[t + s] < redi[t])) {
          redv[t] = redv[t + s];
          redi[t] = redi[t + s];
        }
      }
      __syncthreads();
    }
    chosen[k] = redi[0];
    if (t == 0 && redi[0] < NPTS) persS[redi[0]] = -__builtin_inff();
    __syncthreads();
  }
  float acc = 0.f;
  for (int p = t; p < NPTS; p += 256) {
    int d = death[p];
    if (d < 0) continue;
    bool sal = false;
    for (int c = 0; c < DESTNUM; ++c) sal |= (chosen[c] == p);
    float dv = kde[d];
    float kp = kde[p];
    acc += sal ? ((kp - 1.f) * (kp - 1.f) + dv * dv) : (kp - dv) * (kp - dv);
  }
  redv[t] = acc;
  __syncthreads();
  for (int s = 128; s; s >>= 1) {
    if (t < s) redv[t] += redv[t + s];
    __syncthreads();
  }
  if (t == 0) out[0] = redv[0];
}

extern "C" void kernel_launch(void* const* d_in, const int* in_sizes, int n_in,
                              void* d_out, int out_size, void* d_ws, size_t ws_size,
                              hipStream_t stream) {
  const unsigned short* x = (const unsigned short*)d_in[0];

  float* xT = (float*)d_ws;                       // NPTS*DIM f32 transposed (1 MB)
  float* kde = xT + NPTS * DIM;                   // NPTS f32
  int* scali = (int*)(kde + NPTS);                // [0] = argmin idx
  int* flag = scali + 64;                         // [0] = dtype flag (1=bf16, 0=f32)
  int* order = flag + 64;                         // NPTS (16B-aligned for int4 loads)
  int* rankp = order + NPTS;                      // NPTS
  int* rips = rankp + NPTS;                       // NPTS*KRIPS
  unsigned short* onbr = (unsigned short*)(rips + NPTS * KRIPS);  // NPTS*KRIPS u16
  int* death = (int*)(onbr + NPTS * KRIPS);       // NPTS

  hipLaunchKernelGGL(detect_kernel, dim3(1), dim3(64), 0, stream, x, flag);
  hipLaunchKernelGGL(tr_kernel, dim3(NPTS * DIM / 256), dim3(256), 0, stream, x, flag, xT);
  hipLaunchKernelGGL(knn_kernel, dim3(NPTS), dim3(256), 0, stream, xT, kde, rips);
  hipLaunchKernelGGL(prep_kernel, dim3(1), dim3(256), 0, stream, kde, death, scali);
  hipLaunchKernelGGL(sort_kernel, dim3(1), dim3(256), 0, stream, kde, order, rankp);
  hipLaunchKernelGGL(onbr_kernel, dim3(NPTS * KRIPS / 256), dim3(256), 0, stream,
                     order, rankp, rips, onbr);
  hipLaunchKernelGGL(scan_kernel, dim3(1), dim3(64), 0, stream, order, onbr, death, scali);
  hipLaunchKernelGGL(loss_kernel, dim3(1), dim3(256), 0, stream, kde, death, (float*)d_out);
}